// Round 1
// baseline (534.680 us; speedup 1.0000x reference)
//
#include <hip/hip_runtime.h>
#include <math.h>

#define E 256
#define TD 128
#define NHEAD 8
#define HDIM 32
#define FF 1024
#define NTOK 4096
#define BM 64
#define FC 256

typedef __attribute__((ext_vector_type(8))) __bf16 bf16x8;
typedef __attribute__((ext_vector_type(4))) float f32x4;

__device__ __forceinline__ unsigned short f2bf(float x) {
    unsigned u = __float_as_uint(x);
    u += ((u >> 16) & 1u) + 0x7fffu;   // round-to-nearest-even
    return (unsigned short)(u >> 16);
}
__device__ __forceinline__ float bf2f(unsigned short h) {
    return __uint_as_float(((unsigned)h) << 16);
}

// ---------- kernel 1: weight fp32 -> bf16 (W1:[1024][256], W2:[256][1024], both 262144 elems)
__global__ __launch_bounds__(256) void conv_w_kernel(
    const float* __restrict__ W1, const float* __restrict__ W2,
    unsigned short* __restrict__ w1b, unsigned short* __restrict__ w2b)
{
    int i = blockIdx.x * 256 + threadIdx.x;   // grid = 1024 blocks -> exactly 262144
    w1b[i] = f2bf(W1[i]);
    w2b[i] = f2bf(W2[i]);
}

// ---------- kernel 2: per-batch token pipeline -> folded attention weights
// wkT[b][i][c] = (1/sqrt(HD)) * sum_d k[b,j,h*32+d] * Wq[h*32+d][i]   (c = j*8+h)
// wvv[b][c][o] =               sum_d v[b,j,h*32+d] * Wo[o][h*32+d]
// sbb[b][c]    = (1/sqrt(HD)) * sum_d bq[h*32+d] * k[b,j,h*32+d]
__global__ __launch_bounds__(256) void prep_tokens_kernel(
    const float* __restrict__ tt, const float* __restrict__ bgt,
    const float* __restrict__ Wp, const float* __restrict__ bp,
    const float* __restrict__ g_tok, const float* __restrict__ b_tok,
    const float* __restrict__ Wq, const float* __restrict__ bq,
    const float* __restrict__ Wk, const float* __restrict__ bk,
    const float* __restrict__ Wv, const float* __restrict__ bv,
    const float* __restrict__ Wo,
    float* __restrict__ wkT, float* __restrict__ wvv, float* __restrict__ sbb)
{
    const int bi = blockIdx.x;
    const int t = threadIdx.x;
    const int lane = t & 63;
    __shared__ float kvn[2][E];
    __shared__ float ks[2][E];
    __shared__ float vs[2][E];
    __shared__ float red[8];

    // token projection: tok @ Wp.T + bp
    for (int j = 0; j < 2; ++j) {
        const float* tok = (j == 0 ? tt : bgt) + bi * TD;
        float acc = bp[t];
        for (int i = 0; i < TD; ++i) acc += tok[i] * Wp[t * TD + i];
        kvn[j][t] = acc;
    }
    __syncthreads();
    // layernorm(g_tok, b_tok) per token
    for (int j = 0; j < 2; ++j) {
        float v = kvn[j][t];
        float s = v, s2 = v * v;
        for (int off = 32; off; off >>= 1) { s += __shfl_down(s, off); s2 += __shfl_down(s2, off); }
        if (lane == 0) { red[t >> 6] = s; red[4 + (t >> 6)] = s2; }
        __syncthreads();
        float S  = red[0] + red[1] + red[2] + red[3];
        float S2 = red[4] + red[5] + red[6] + red[7];
        float m = S * (1.f / E);
        float rs = rsqrtf(S2 * (1.f / E) - m * m + 1e-5f);
        __syncthreads();
        kvn[j][t] = (v - m) * rs * g_tok[t] + b_tok[t];
    }
    __syncthreads();
    // k, v projections
    for (int j = 0; j < 2; ++j) {
        float ak = bk[t], av = bv[t];
        for (int i = 0; i < E; ++i) {
            float x = kvn[j][i];
            ak += x * Wk[t * E + i];
            av += x * Wv[t * E + i];
        }
        ks[j][t] = ak; vs[j][t] = av;
    }
    __syncthreads();
    const float inv = 0.17677669529663687f;  // 1/sqrt(32)
    for (int c = 0; c < 16; ++c) {
        int j = c >> 3, h = c & 7;
        float awk = 0.f, awv = 0.f;
        for (int d = 0; d < HDIM; ++d) {
            awk += ks[j][h * HDIM + d] * Wq[(h * HDIM + d) * E + t];
            awv += vs[j][h * HDIM + d] * Wo[t * E + (h * HDIM + d)];
        }
        wkT[(bi * E + t) * 16 + c] = awk * inv;   // transposed for coalesced score reads
        wvv[(bi * 16 + c) * E + t] = awv;
    }
    if (t < 16) {
        int j = t >> 3, h = t & 7;
        float s = 0.f;
        for (int d = 0; d < HDIM; ++d) s += bq[h * HDIM + d] * ks[j][h * HDIM + d];
        sbb[bi * 16 + t] = s * inv;
    }
}

// ---------- kernel 3: fused main — 64 rows/block, 256 threads (4 waves)
__global__ __launch_bounds__(256, 1) void fused_main_kernel(
    const float* __restrict__ img,
    const float* __restrict__ g_img, const float* __restrict__ b_img,
    const float* __restrict__ g_ffn, const float* __restrict__ b_ffn,
    const float* __restrict__ pbo, const float* __restrict__ pb1, const float* __restrict__ pb2,
    const unsigned short* __restrict__ w1b, const unsigned short* __restrict__ w2b,
    const float* __restrict__ wkT, const float* __restrict__ wvv, const float* __restrict__ sbb,
    float* __restrict__ out)
{
    __shared__ float xs[BM][E + 2];             // x, then x1 (fp32 for residual precision)
    __shared__ unsigned short ns[BM][E + 8];    // bf16 LN output (pad 8 -> 2-way-max bank alias)
    __shared__ unsigned short hs[BM][FC + 8];   // bf16 gelu chunk
    __shared__ float mean_s[BM], rstd_s[BM];
    __shared__ float sc_s[BM][16];
    __shared__ float a_s[BM][16];

    const int t = threadIdx.x;
    const int lane = t & 63;
    const int wid = t >> 6;
    const int l15 = lane & 15;
    const int l4 = lane >> 4;
    const int bi = blockIdx.x >> 6;
    const int n0 = (blockIdx.x & 63) << 6;

    const float* imgb = img + (size_t)bi * E * NTOK + n0;

    // Phase 0: coalesced transpose-load: xs[n][e] = img[b][e][n0+n]
    for (int e0 = 0; e0 < E; e0 += 4) {
        int e = e0 + wid;
        xs[lane][e] = imgb[(size_t)e * NTOK + lane];
    }
    __syncthreads();

    // Phase 1: LN1 stats (each wave owns 16 rows)
    for (int rr = 0; rr < 16; ++rr) {
        int r = wid * 16 + rr;
        float v0 = xs[r][lane], v1 = xs[r][lane + 64], v2 = xs[r][lane + 128], v3 = xs[r][lane + 192];
        float s = v0 + v1 + v2 + v3;
        float s2 = v0 * v0 + v1 * v1 + v2 * v2 + v3 * v3;
        for (int off = 32; off; off >>= 1) { s += __shfl_down(s, off); s2 += __shfl_down(s2, off); }
        if (lane == 0) {
            float m = s * (1.f / E);
            mean_s[r] = m;
            rstd_s[r] = rsqrtf(s2 * (1.f / E) - m * m + 1e-5f);
        }
    }
    __syncthreads();

    // Phase 2: ns = bf16(LN1(x))
    {
        float ge = g_img[t], be = b_img[t];
        for (int r = 0; r < BM; ++r)
            ns[r][t] = f2bf((xs[r][t] - mean_s[r]) * rstd_s[r] * ge + be);
    }
    __syncthreads();

    // Phase 3a: scores (pre-scaled; 4 threads per row, 4 (j,h)-combos each)
    {
        const float* wkb = wkT + (size_t)bi * E * 16;
        const int r = t >> 2, q = t & 3;
        const float* ps = sbb + bi * 16 + q * 4;
        float s0 = ps[0], s1 = ps[1], s2 = ps[2], s3 = ps[3];
        for (int i = 0; i < E; ++i) {
            float nv = bf2f(ns[r][i]);
            f32x4 w4 = *(const f32x4*)(wkb + i * 16 + q * 4);
            s0 += nv * w4[0]; s1 += nv * w4[1]; s2 += nv * w4[2]; s3 += nv * w4[3];
        }
        sc_s[r][q * 4 + 0] = s0; sc_s[r][q * 4 + 1] = s1;
        sc_s[r][q * 4 + 2] = s2; sc_s[r][q * 4 + 3] = s3;
    }
    __syncthreads();

    // Phase 3b: softmax over the 2 tokens per (row, head)
    for (int idx = t; idx < BM * NHEAD; idx += 256) {
        int r = idx >> 3, h = idx & 7;
        float s0 = sc_s[r][h], s1 = sc_s[r][8 + h];
        float m = fmaxf(s0, s1);
        float e0 = expf(s0 - m), e1 = expf(s1 - m);
        float is = 1.f / (e0 + e1);
        a_s[r][h] = e0 * is;
        a_s[r][8 + h] = e1 * is;
    }
    __syncthreads();

    // Phase 3c: attended + residual -> xs becomes x1
    {
        const float* wvb = wvv + (size_t)bi * 16 * E;
        float wvc[16];
        #pragma unroll
        for (int c = 0; c < 16; ++c) wvc[c] = wvb[c * E + t];
        float bov = pbo[t];
        for (int r = 0; r < BM; ++r) {
            float acc = bov;
            #pragma unroll
            for (int c = 0; c < 16; ++c) acc += a_s[r][c] * wvc[c];
            xs[r][t] += acc;
        }
    }
    __syncthreads();

    // Phase 4: LN2 stats on x1
    for (int rr = 0; rr < 16; ++rr) {
        int r = wid * 16 + rr;
        float v0 = xs[r][lane], v1 = xs[r][lane + 64], v2 = xs[r][lane + 128], v3 = xs[r][lane + 192];
        float s = v0 + v1 + v2 + v3;
        float s2 = v0 * v0 + v1 * v1 + v2 * v2 + v3 * v3;
        for (int off = 32; off; off >>= 1) { s += __shfl_down(s, off); s2 += __shfl_down(s2, off); }
        if (lane == 0) {
            float m = s * (1.f / E);
            mean_s[r] = m;
            rstd_s[r] = rsqrtf(s2 * (1.f / E) - m * m + 1e-5f);
        }
    }
    __syncthreads();

    // Phase 5: ns = bf16(LN2(x1))
    {
        float ge = g_ffn[t], be = b_ffn[t];
        for (int r = 0; r < BM; ++r)
            ns[r][t] = f2bf((xs[r][t] - mean_s[r]) * rstd_s[r] * ge + be);
    }
    __syncthreads();

    // ---- FFN via MFMA 16x16x32 bf16. Wave wid owns 64 output cols; 4 M-tiles x 4 N-tiles.
    f32x4 acc2[4][4];
    #pragma unroll
    for (int m = 0; m < 4; ++m)
        #pragma unroll
        for (int n = 0; n < 4; ++n)
            acc2[m][n] = f32x4{0.f, 0.f, 0.f, 0.f};

    for (int fc = 0; fc < FF; fc += FC) {
        // GEMM1: p = ns @ W1_chunk.T   (A: lane row=l15, k=l4*8+j; B[k][n]=W1[f(n)][k])
        f32x4 p[4][4];
        #pragma unroll
        for (int m = 0; m < 4; ++m)
            #pragma unroll
            for (int n = 0; n < 4; ++n)
                p[m][n] = f32x4{0.f, 0.f, 0.f, 0.f};

        for (int kk = 0; kk < 8; ++kk) {
            bf16x8 af[4], bfr[4];
            #pragma unroll
            for (int m = 0; m < 4; ++m)
                af[m] = *(const bf16x8*)&ns[m * 16 + l15][kk * 32 + l4 * 8];
            #pragma unroll
            for (int n = 0; n < 4; ++n)
                bfr[n] = *(const bf16x8*)&w1b[(size_t)(fc + wid * 64 + n * 16 + l15) * E + kk * 32 + l4 * 8];
            #pragma unroll
            for (int m = 0; m < 4; ++m)
                #pragma unroll
                for (int n = 0; n < 4; ++n)
                    p[m][n] = __builtin_amdgcn_mfma_f32_16x16x32_bf16(af[m], bfr[n], p[m][n], 0, 0, 0);
        }
        // bias + exact gelu -> hs (bf16). D layout: row=(l>>4)*4+reg, col=l&15 (verified m89)
        {
            float b1v[4];
            #pragma unroll
            for (int n = 0; n < 4; ++n) b1v[n] = pb1[fc + wid * 64 + n * 16 + l15];
            #pragma unroll
            for (int m = 0; m < 4; ++m)
                #pragma unroll
                for (int n = 0; n < 4; ++n)
                    #pragma unroll
                    for (int rg = 0; rg < 4; ++rg) {
                        float x = p[m][n][rg] + b1v[n];
                        float g = 0.5f * x * (1.f + erff(x * 0.70710678118654752f));
                        hs[m * 16 + l4 * 4 + rg][wid * 64 + n * 16 + l15] = f2bf(g);
                    }
        }
        __syncthreads();
        // GEMM2: acc2 += hs @ W2_chunk.T  (B[k=f][o] = W2[o][fc+f])
        for (int kk = 0; kk < 8; ++kk) {
            bf16x8 af[4], bfr[4];
            #pragma unroll
            for (int m = 0; m < 4; ++m)
                af[m] = *(const bf16x8*)&hs[m * 16 + l15][kk * 32 + l4 * 8];
            #pragma unroll
            for (int n = 0; n < 4; ++n)
                bfr[n] = *(const bf16x8*)&w2b[(size_t)(wid * 64 + n * 16 + l15) * FF + fc + kk * 32 + l4 * 8];
            #pragma unroll
            for (int m = 0; m < 4; ++m)
                #pragma unroll
                for (int n = 0; n < 4; ++n)
                    acc2[m][n] = __builtin_amdgcn_mfma_f32_16x16x32_bf16(af[m], bfr[n], acc2[m][n], 0, 0, 0);
        }
        __syncthreads();   // hs consumed; safe to overwrite next chunk
    }

    // Epilogue: out = x1 + ffn + b2 (each (r,o) owned by exactly one thread/reg)
    {
        float b2v[4];
        #pragma unroll
        for (int n = 0; n < 4; ++n) b2v[n] = pb2[wid * 64 + n * 16 + l15];
        #pragma unroll
        for (int m = 0; m < 4; ++m)
            #pragma unroll
            for (int n = 0; n < 4; ++n)
                #pragma unroll
                for (int rg = 0; rg < 4; ++rg)
                    xs[m * 16 + l4 * 4 + rg][wid * 64 + n * 16 + l15] += acc2[m][n][rg] + b2v[n];
    }
    __syncthreads();

    // Writeback: coalesced transpose store out[b][e][n0+n] = xs[n][e]
    float* outb = out + (size_t)bi * E * NTOK + n0;
    for (int e0 = 0; e0 < E; e0 += 4) {
        int e = e0 + wid;
        outb[(size_t)e * NTOK + lane] = xs[lane][e];
    }
}

extern "C" void kernel_launch(void* const* d_in, const int* in_sizes, int n_in,
                              void* d_out, int out_size, void* d_ws, size_t ws_size,
                              hipStream_t stream) {
    (void)in_sizes; (void)n_in; (void)out_size; (void)ws_size;
    const float* img   = (const float*)d_in[0];
    const float* tt    = (const float*)d_in[1];
    const float* bgt   = (const float*)d_in[2];
    const float* Wp    = (const float*)d_in[3];
    const float* bp    = (const float*)d_in[4];
    const float* g_img = (const float*)d_in[5];
    const float* b_img = (const float*)d_in[6];
    const float* g_tok = (const float*)d_in[7];
    const float* b_tok = (const float*)d_in[8];
    const float* g_ffn = (const float*)d_in[9];
    const float* b_ffn = (const float*)d_in[10];
    const float* Wq    = (const float*)d_in[11];
    const float* Wk    = (const float*)d_in[12];
    const float* Wv    = (const float*)d_in[13];
    const float* bq    = (const float*)d_in[14];
    const float* bk    = (const float*)d_in[15];
    const float* bv    = (const float*)d_in[16];
    const float* Wo    = (const float*)d_in[17];
    const float* bo    = (const float*)d_in[18];
    const float* W1    = (const float*)d_in[19];
    const float* b1    = (const float*)d_in[20];
    const float* W2    = (const float*)d_in[21];
    const float* b2    = (const float*)d_in[22];

    char* ws = (char*)d_ws;
    unsigned short* w1b = (unsigned short*)(ws);              // 512 KB
    unsigned short* w2b = (unsigned short*)(ws + 524288);     // 512 KB
    float* wkT = (float*)(ws + 1048576);                      // 256 KB
    float* wvv = (float*)(ws + 1310720);                      // 256 KB
    float* sbb = (float*)(ws + 1572864);                      // 1 KB

    hipLaunchKernelGGL(conv_w_kernel, dim3(1024), dim3(256), 0, stream, W1, W2, w1b, w2b);
    hipLaunchKernelGGL(prep_tokens_kernel, dim3(16), dim3(256), 0, stream,
                       tt, bgt, Wp, bp, g_tok, b_tok, Wq, bq, Wk, bk, Wv, bv, Wo,
                       wkT, wvv, sbb);
    hipLaunchKernelGGL(fused_main_kernel, dim3(1024), dim3(256), 0, stream,
                       img, g_img, b_img, g_ffn, b_ffn, bo, b1, b2,
                       w1b, w2b, wkT, wvv, sbb, (float*)d_out);
}

// Round 2
// 387.629 us; speedup vs baseline: 1.3794x; 1.3794x over previous
//
#include <hip/hip_runtime.h>
#include <math.h>

#define E 256
#define TD 128
#define FF 1024
#define NTOK 4096
#define BM 64
#define FC 256
#define XS_LD 258   // u16 stride for xs   (row-to-row bank shift = 1 -> column writes conflict-free)
#define NS_LD 264   // u16 stride for ns/hs (528 B = 16 mod 128 -> b128 row reads 2-way/free)
#define OUT_LD 257  // f32 stride for outs (column reads conflict-free)

typedef __attribute__((ext_vector_type(8))) __bf16 bf16x8;
typedef __attribute__((ext_vector_type(4))) float f32x4;

__device__ __forceinline__ unsigned short f2bf(float x) {
    unsigned u = __float_as_uint(x);
    u += ((u >> 16) & 1u) + 0x7fffu;   // RNE
    return (unsigned short)(u >> 16);
}
__device__ __forceinline__ float bf2f(unsigned short h) {
    return __uint_as_float(((unsigned)h) << 16);
}
__device__ __forceinline__ float gelu_tanh(float x) {
    // tanh-form gelu; |err vs exact| < ~1e-3, well under harness threshold
    float u = 0.7978845608028654f * (x + 0.044715f * x * x * x);
    float e = __expf(2.f * u);
    float th = 1.f - 2.f / (e + 1.f);
    return 0.5f * x * (1.f + th);
}

// ---------- prep kernel: blocks 0..255 convert W1/W2 to bf16; blocks 256..271 token pipeline
__global__ __launch_bounds__(256) void prep_kernel(
    const float* __restrict__ W1, const float* __restrict__ W2,
    const float* __restrict__ tt, const float* __restrict__ bgt,
    const float* __restrict__ Wp, const float* __restrict__ bp,
    const float* __restrict__ g_tok, const float* __restrict__ b_tok,
    const float* __restrict__ Wq, const float* __restrict__ bq,
    const float* __restrict__ Wk, const float* __restrict__ bk,
    const float* __restrict__ Wv, const float* __restrict__ bv,
    const float* __restrict__ Wo,
    unsigned short* __restrict__ w1b, unsigned short* __restrict__ w2b,
    unsigned short* __restrict__ wkbf, float* __restrict__ wvv, float* __restrict__ sbb)
{
    const int t = threadIdx.x;
    if (blockIdx.x < 256) {
        int i = (blockIdx.x * 256 + t) * 4;
        f32x4 a = *(const f32x4*)(W1 + i);
        f32x4 b = *(const f32x4*)(W2 + i);
        ushort4 oa, ob;
        oa.x = f2bf(a[0]); oa.y = f2bf(a[1]); oa.z = f2bf(a[2]); oa.w = f2bf(a[3]);
        ob.x = f2bf(b[0]); ob.y = f2bf(b[1]); ob.z = f2bf(b[2]); ob.w = f2bf(b[3]);
        *(ushort4*)(w1b + i) = oa;
        *(ushort4*)(w2b + i) = ob;
        return;
    }
    const int bi = blockIdx.x - 256;
    const int lane = t & 63;
    __shared__ float kvn[2][E];
    __shared__ float ks[2][E];
    __shared__ float vs[2][E];
    __shared__ float red[8];

    for (int j = 0; j < 2; ++j) {
        const float* tok = (j == 0 ? tt : bgt) + bi * TD;
        float acc = bp[t];
        for (int i = 0; i < TD; ++i) acc += tok[i] * Wp[t * TD + i];
        kvn[j][t] = acc;
    }
    __syncthreads();
    for (int j = 0; j < 2; ++j) {
        float v = kvn[j][t];
        float s = v, s2 = v * v;
        for (int off = 32; off; off >>= 1) { s += __shfl_down(s, off); s2 += __shfl_down(s2, off); }
        if (lane == 0) { red[t >> 6] = s; red[4 + (t >> 6)] = s2; }
        __syncthreads();
        float S  = red[0] + red[1] + red[2] + red[3];
        float S2 = red[4] + red[5] + red[6] + red[7];
        float m = S * (1.f / E);
        float rs = rsqrtf(S2 * (1.f / E) - m * m + 1e-5f);
        __syncthreads();
        kvn[j][t] = (v - m) * rs * g_tok[t] + b_tok[t];
    }
    __syncthreads();
    for (int j = 0; j < 2; ++j) {
        float ak = bk[t], av = bv[t];
        for (int i = 0; i < E; ++i) {
            float x = kvn[j][i];
            ak += x * Wk[t * E + i];
            av += x * Wv[t * E + i];
        }
        ks[j][t] = ak; vs[j][t] = av;
    }
    __syncthreads();
    const float inv = 0.17677669529663687f;  // 1/sqrt(32)
    for (int c = 0; c < 16; ++c) {
        int j = c >> 3, h = c & 7;
        float awk = 0.f, awv = 0.f;
        for (int d = 0; d < 32; ++d) {
            awk += ks[j][h * 32 + d] * Wq[(h * 32 + d) * E + t];
            awv += vs[j][h * 32 + d] * Wo[t * E + (h * 32 + d)];
        }
        wkbf[(bi * 16 + c) * E + t] = f2bf(awk * inv);   // [c][k] layout: B-fragment friendly
        wvv[(bi * 16 + c) * E + t] = awv;
    }
    if (t < 16) {
        int j = t >> 3, h = t & 7;
        float s = 0.f;
        for (int d = 0; d < 32; ++d) s += bq[h * 32 + d] * ks[j][h * 32 + d];
        sbb[bi * 16 + t] = s * inv;
    }
}

// ---------- fused main: 64 rows/block, 512 threads (8 waves), 2 blocks/CU
__global__ __launch_bounds__(512, 4) void fused_main_kernel(
    const float* __restrict__ img,
    const float* __restrict__ g_img, const float* __restrict__ b_img,
    const float* __restrict__ g_ffn, const float* __restrict__ b_ffn,
    const float* __restrict__ pbo, const float* __restrict__ pb1, const float* __restrict__ pb2,
    const unsigned short* __restrict__ w1b, const unsigned short* __restrict__ w2b,
    const unsigned short* __restrict__ wkbf, const float* __restrict__ wvv,
    const float* __restrict__ sbb,
    unsigned short* __restrict__ x1ws, float* __restrict__ out)
{
    __shared__ __align__(16) char smem[67584];
    unsigned short (*xs)[XS_LD] = (unsigned short(*)[XS_LD])smem;          // x then x1 (bf16)
    unsigned short (*hs)[NS_LD] = (unsigned short(*)[NS_LD])smem;          // aliases xs (FFN phase)
    unsigned short (*ns)[NS_LD] = (unsigned short(*)[NS_LD])(smem + 33792);// LN out (bf16)
    float (*outs)[OUT_LD] = (float(*)[OUT_LD])smem;                        // aliases everything (epilogue)
    __shared__ float sc_s[BM][16];          // scores, then attn weights (in-place)
    __shared__ float mean_s[BM], rstd_s[BM];

    const int t = threadIdx.x;
    const int lane = t & 63;
    const int wid = t >> 6;
    const int l15 = lane & 15;
    const int l4 = lane >> 4;
    const int bi = blockIdx.x >> 6;
    const int n0 = (blockIdx.x & 63) << 6;

    const float* imgb = img + (size_t)bi * E * NTOK + n0;

    // Phase 0: transpose-load -> bf16 xs
    for (int e0 = 0; e0 < E; e0 += 8) {
        int e = e0 + wid;
        xs[lane][e] = f2bf(imgb[(size_t)e * NTOK + lane]);
    }
    __syncthreads();

    // Phase 1: LN1 stats — wave owns 8 rows
    for (int rr = 0; rr < 8; ++rr) {
        int r = wid * 8 + rr;
        float v0 = bf2f(xs[r][lane]),       v1 = bf2f(xs[r][lane + 64]);
        float v2 = bf2f(xs[r][lane + 128]), v3 = bf2f(xs[r][lane + 192]);
        float s = v0 + v1 + v2 + v3;
        float s2 = v0 * v0 + v1 * v1 + v2 * v2 + v3 * v3;
        for (int off = 32; off; off >>= 1) { s += __shfl_down(s, off); s2 += __shfl_down(s2, off); }
        if (lane == 0) {
            float m = s * (1.f / E);
            mean_s[r] = m;
            rstd_s[r] = rsqrtf(s2 * (1.f / E) - m * m + 1e-5f);
        }
    }
    __syncthreads();

    // Phase 2: ns = bf16(LN1(x)); thread owns col c for 32 rows
    {
        int c = t & 255, r0 = t >> 8;
        float ge = g_img[c], be = b_img[c];
        for (int i = 0; i < 32; ++i) {
            int r = r0 + 2 * i;
            ns[r][c] = f2bf((bf2f(xs[r][c]) - mean_s[r]) * rstd_s[r] * ge + be);
        }
    }
    __syncthreads();

    // Phase 3a: scores via MFMA (waves 0-3, m-tile = wid; N=16 score cols)
    if (wid < 4) {
        f32x4 p = {0.f, 0.f, 0.f, 0.f};
        const unsigned short* wkb = wkbf + (size_t)bi * 16 * E;
        for (int kk = 0; kk < 8; ++kk) {
            bf16x8 a = *(const bf16x8*)&ns[wid * 16 + l15][kk * 32 + l4 * 8];
            bf16x8 b = *(const bf16x8*)&wkb[(size_t)l15 * E + kk * 32 + l4 * 8];
            p = __builtin_amdgcn_mfma_f32_16x16x32_bf16(a, b, p, 0, 0, 0);
        }
        float sb = sbb[bi * 16 + l15];
        #pragma unroll
        for (int rg = 0; rg < 4; ++rg)
            sc_s[wid * 16 + l4 * 4 + rg][l15] = p[rg] + sb;
    }
    __syncthreads();

    // Phase 3b: softmax over 2 tokens per (row, head) — exactly 1 per thread, in-place
    {
        int r = t >> 3, h = t & 7;
        float s0 = sc_s[r][h], s1 = sc_s[r][8 + h];
        float m = fmaxf(s0, s1);
        float e0 = __expf(s0 - m), e1 = __expf(s1 - m);
        float is = 1.f / (e0 + e1);
        sc_s[r][h] = e0 * is;
        sc_s[r][8 + h] = e1 * is;
    }
    __syncthreads();

    // Phase 3c: attended + residual -> x1 (bf16 in xs, and to global x1ws)
    {
        int o = t & 255, r0 = (t >> 8) * 32;
        const float* wvb = wvv + (size_t)bi * 16 * E;
        float wvc[16];
        #pragma unroll
        for (int c = 0; c < 16; ++c) wvc[c] = wvb[c * E + o];
        float bov = pbo[o];
        unsigned short* x1p = x1ws + ((size_t)(bi * NTOK + n0 + r0)) * E + o;
        for (int r = r0; r < r0 + 32; ++r) {
            float acc = bov;
            #pragma unroll
            for (int c = 0; c < 16; ++c) acc += sc_s[r][c] * wvc[c];
            float x1 = bf2f(xs[r][o]) + acc;
            unsigned short h16 = f2bf(x1);
            xs[r][o] = h16;
            x1p[(size_t)(r - r0) * E] = h16;
        }
    }
    __syncthreads();

    // Phase 4: LN2 stats on x1
    for (int rr = 0; rr < 8; ++rr) {
        int r = wid * 8 + rr;
        float v0 = bf2f(xs[r][lane]),       v1 = bf2f(xs[r][lane + 64]);
        float v2 = bf2f(xs[r][lane + 128]), v3 = bf2f(xs[r][lane + 192]);
        float s = v0 + v1 + v2 + v3;
        float s2 = v0 * v0 + v1 * v1 + v2 * v2 + v3 * v3;
        for (int off = 32; off; off >>= 1) { s += __shfl_down(s, off); s2 += __shfl_down(s2, off); }
        if (lane == 0) {
            float m = s * (1.f / E);
            mean_s[r] = m;
            rstd_s[r] = rsqrtf(s2 * (1.f / E) - m * m + 1e-5f);
        }
    }
    __syncthreads();

    // Phase 5: ns = bf16(LN2(x1))
    {
        int c = t & 255, r0 = t >> 8;
        float ge = g_ffn[c], be = b_ffn[c];
        for (int i = 0; i < 32; ++i) {
            int r = r0 + 2 * i;
            ns[r][c] = f2bf((bf2f(xs[r][c]) - mean_s[r]) * rstd_s[r] * ge + be);
        }
    }
    __syncthreads();   // xs dead after this point; hs may reuse its storage

    // ---- FFN: wave owns 32 output cols (2 n-tiles), 4 m-tiles
    const int nc = wid * 32;
    f32x4 acc2[4][2];
    #pragma unroll
    for (int m = 0; m < 4; ++m)
        #pragma unroll
        for (int n = 0; n < 2; ++n)
            acc2[m][n] = f32x4{0.f, 0.f, 0.f, 0.f};

    for (int fc = 0; fc < FF; fc += FC) {
        f32x4 p[4][2];
        #pragma unroll
        for (int m = 0; m < 4; ++m)
            #pragma unroll
            for (int n = 0; n < 2; ++n)
                p[m][n] = f32x4{0.f, 0.f, 0.f, 0.f};

        for (int kk = 0; kk < 8; ++kk) {
            bf16x8 af[4], bfr[2];
            #pragma unroll
            for (int m = 0; m < 4; ++m)
                af[m] = *(const bf16x8*)&ns[m * 16 + l15][kk * 32 + l4 * 8];
            #pragma unroll
            for (int n = 0; n < 2; ++n)
                bfr[n] = *(const bf16x8*)&w1b[(size_t)(fc + nc + n * 16 + l15) * E + kk * 32 + l4 * 8];
            #pragma unroll
            for (int m = 0; m < 4; ++m)
                #pragma unroll
                for (int n = 0; n < 2; ++n)
                    p[m][n] = __builtin_amdgcn_mfma_f32_16x16x32_bf16(af[m], bfr[n], p[m][n], 0, 0, 0);
        }
        {
            float b1v[2];
            #pragma unroll
            for (int n = 0; n < 2; ++n) b1v[n] = pb1[fc + nc + n * 16 + l15];
            #pragma unroll
            for (int m = 0; m < 4; ++m)
                #pragma unroll
                for (int n = 0; n < 2; ++n)
                    #pragma unroll
                    for (int rg = 0; rg < 4; ++rg) {
                        float x = p[m][n][rg] + b1v[n];
                        hs[m * 16 + l4 * 4 + rg][nc + n * 16 + l15] = f2bf(gelu_tanh(x));
                    }
        }
        __syncthreads();
        for (int kk = 0; kk < 8; ++kk) {
            bf16x8 af[4], bfr[2];
            #pragma unroll
            for (int m = 0; m < 4; ++m)
                af[m] = *(const bf16x8*)&hs[m * 16 + l15][kk * 32 + l4 * 8];
            #pragma unroll
            for (int n = 0; n < 2; ++n)
                bfr[n] = *(const bf16x8*)&w2b[(size_t)(nc + n * 16 + l15) * FF + fc + kk * 32 + l4 * 8];
            #pragma unroll
            for (int m = 0; m < 4; ++m)
                #pragma unroll
                for (int n = 0; n < 2; ++n)
                    acc2[m][n] = __builtin_amdgcn_mfma_f32_16x16x32_bf16(af[m], bfr[n], acc2[m][n], 0, 0, 0);
        }
        __syncthreads();
    }

    // Epilogue: outs[row][col] = x1 + ffn + b2 (outs aliases ns/hs — all dead)
    {
        float b2v[2];
        #pragma unroll
        for (int n = 0; n < 2; ++n) b2v[n] = pb2[nc + n * 16 + l15];
        const unsigned short* x1r = x1ws + ((size_t)(bi * NTOK + n0)) * E;
        #pragma unroll
        for (int m = 0; m < 4; ++m)
            #pragma unroll
            for (int rg = 0; rg < 4; ++rg) {
                int row = m * 16 + l4 * 4 + rg;
                #pragma unroll
                for (int n = 0; n < 2; ++n) {
                    int col = nc + n * 16 + l15;
                    outs[row][col] = bf2f(x1r[(size_t)row * E + col]) + acc2[m][n][rg] + b2v[n];
                }
            }
    }
    __syncthreads();

    // Writeback: transpose store
    float* outb = out + (size_t)bi * E * NTOK + n0;
    for (int e0 = 0; e0 < E; e0 += 8) {
        int e = e0 + wid;
        outb[(size_t)e * NTOK + lane] = outs[lane][e];
    }
}

extern "C" void kernel_launch(void* const* d_in, const int* in_sizes, int n_in,
                              void* d_out, int out_size, void* d_ws, size_t ws_size,
                              hipStream_t stream) {
    (void)in_sizes; (void)n_in; (void)out_size; (void)ws_size;
    const float* img   = (const float*)d_in[0];
    const float* tt    = (const float*)d_in[1];
    const float* bgt   = (const float*)d_in[2];
    const float* Wp    = (const float*)d_in[3];
    const float* bp    = (const float*)d_in[4];
    const float* g_img = (const float*)d_in[5];
    const float* b_img = (const float*)d_in[6];
    const float* g_tok = (const float*)d_in[7];
    const float* b_tok = (const float*)d_in[8];
    const float* g_ffn = (const float*)d_in[9];
    const float* b_ffn = (const float*)d_in[10];
    const float* Wq    = (const float*)d_in[11];
    const float* Wk    = (const float*)d_in[12];
    const float* Wv    = (const float*)d_in[13];
    const float* bq    = (const float*)d_in[14];
    const float* bk    = (const float*)d_in[15];
    const float* bv    = (const float*)d_in[16];
    const float* Wo    = (const float*)d_in[17];
    const float* bo    = (const float*)d_in[18];
    const float* W1    = (const float*)d_in[19];
    const float* b1    = (const float*)d_in[20];
    const float* W2    = (const float*)d_in[21];
    const float* b2    = (const float*)d_in[22];

    char* ws = (char*)d_ws;
    unsigned short* w1b  = (unsigned short*)(ws);                 // 512 KB
    unsigned short* w2b  = (unsigned short*)(ws + 524288);        // 512 KB
    unsigned short* wkbf = (unsigned short*)(ws + 1048576);       // 128 KB  [16 b][16 c][256 k] bf16
    float*          wvv  = (float*)(ws + 1179648);                // 256 KB  [16 b][16 c][256 o] f32
    float*          sbb  = (float*)(ws + 1441792);                // 1 KB
    unsigned short* x1ws = (unsigned short*)(ws + 1442816);       // 32 MB   [16 b][4096 n][256 e] bf16

    hipLaunchKernelGGL(prep_kernel, dim3(272), dim3(256), 0, stream,
                       W1, W2, tt, bgt, Wp, bp, g_tok, b_tok, Wq, bq, Wk, bk, Wv, bv, Wo,
                       w1b, w2b, wkbf, wvv, sbb);
    hipLaunchKernelGGL(fused_main_kernel, dim3(1024), dim3(512), 0, stream,
                       img, g_img, b_img, g_ffn, b_ffn, bo, b1, b2,
                       w1b, w2b, wkbf, wvv, sbb, x1ws, (float*)d_out);
}

// Round 3
// 286.792 us; speedup vs baseline: 1.8643x; 1.3516x over previous
//
#include <hip/hip_runtime.h>
#include <math.h>

#define E 256
#define TD 128
#define FF 1024
#define NTOK 4096
#define BM 64
#define XS_LD 264   // u16; 528B row = 132 words == 4 mod 32 -> b128 16-row reads 2-way (free), 16B aligned
#define HS_LD 264
#define A_LD 40     // u16; 80B row, 16B aligned, 20 words == 20 mod 32 -> 2-way
#define OUT_LD 257  // f32

typedef __attribute__((ext_vector_type(8))) __bf16 bf16x8;
typedef __attribute__((ext_vector_type(4))) float f32x4;

__device__ __forceinline__ unsigned short f2bf(float x) {
    unsigned u = __float_as_uint(x);
    u += ((u >> 16) & 1u) + 0x7fffu;   // RNE
    return (unsigned short)(u >> 16);
}
__device__ __forceinline__ float bf2f(unsigned short h) {
    return __uint_as_float(((unsigned)h) << 16);
}
__device__ __forceinline__ float gelu_tanh(float x) {
    float u = 0.7978845608028654f * (x + 0.044715f * x * x * x);
    float e = __expf(2.f * u);
    float th = 1.f - 2.f / (e + 1.f);
    return 0.5f * x * (1.f + th);
}

// ---------------- prep kernel ----------------
// blocks 0..255: W1 rows 4b..4b+3 -> g_ffn-scaled bf16 + G1/B1 reduction; W2 -> bf16
// blocks 256..271: per-batch token pipeline -> wkbf (g_img-scaled), wvbf (K=32 padded), Gk, sbk
__global__ __launch_bounds__(256) void prep_kernel(
    const float* __restrict__ W1, const float* __restrict__ W2, const float* __restrict__ b1,
    const float* __restrict__ tt, const float* __restrict__ bgt,
    const float* __restrict__ Wp, const float* __restrict__ bp,
    const float* __restrict__ g_tok, const float* __restrict__ b_tok,
    const float* __restrict__ g_img, const float* __restrict__ b_img,
    const float* __restrict__ Wq, const float* __restrict__ bq,
    const float* __restrict__ Wk, const float* __restrict__ bk,
    const float* __restrict__ Wv, const float* __restrict__ bv,
    const float* __restrict__ Wo,
    const float* __restrict__ g_ffn, const float* __restrict__ b_ffn,
    unsigned short* __restrict__ w1b, unsigned short* __restrict__ w2b,
    unsigned short* __restrict__ wkbf, unsigned short* __restrict__ wvbf,
    float* __restrict__ Gk, float* __restrict__ sbk,
    float* __restrict__ G1, float* __restrict__ B1)
{
    const int t = threadIdx.x;
    const int lane = t & 63;
    if (blockIdx.x < 256) {
        const int b = blockIdx.x;
        // W1: rows 4b + (t>>6); lane covers k via f32x4
        {
            int row = b * 4 + (t >> 6);
            int i0 = lane * 4;
            f32x4 w = *(const f32x4*)(W1 + (size_t)row * E + i0);
            f32x4 g = *(const f32x4*)(g_ffn + i0);
            f32x4 bb = *(const f32x4*)(b_ffn + i0);
            float s0 = w[0] * g[0], s1 = w[1] * g[1], s2 = w[2] * g[2], s3 = w[3] * g[3];
            ushort4 o; o.x = f2bf(s0); o.y = f2bf(s1); o.z = f2bf(s2); o.w = f2bf(s3);
            *(ushort4*)(w1b + (size_t)row * E + i0) = o;
            float gp = s0 + s1 + s2 + s3;
            float bpv = w[0] * bb[0] + w[1] * bb[1] + w[2] * bb[2] + w[3] * bb[3];
            for (int off = 32; off; off >>= 1) { gp += __shfl_down(gp, off); bpv += __shfl_down(bpv, off); }
            if (lane == 0) { G1[row] = gp; B1[row] = bpv + b1[row]; }
        }
        // W2: plain bf16 convert
        {
            int i = (b * 256 + t) * 4;
            f32x4 w = *(const f32x4*)(W2 + i);
            ushort4 o; o.x = f2bf(w[0]); o.y = f2bf(w[1]); o.z = f2bf(w[2]); o.w = f2bf(w[3]);
            *(ushort4*)(w2b + i) = o;
        }
        return;
    }
    const int bi = blockIdx.x - 256;
    __shared__ float tokL[2][TD];
    __shared__ float kvn[2][E];
    __shared__ float ks[2][E];
    __shared__ float vs[2][E];
    __shared__ float red[8];
    __shared__ float redk[16][4], redb[16][4];

    if (t < TD) tokL[0][t] = tt[bi * TD + t];
    else tokL[1][t - TD] = bgt[bi * TD + (t - TD)];
    __syncthreads();

    // token projection (both tokens share the Wp row read)
    {
        float a0 = bp[t], a1 = a0;
        const float* wr = Wp + (size_t)t * TD;
        for (int i = 0; i < TD; i += 4) {
            f32x4 w = *(const f32x4*)(wr + i);
            f32x4 x0 = *(const f32x4*)(&tokL[0][i]);
            f32x4 x1 = *(const f32x4*)(&tokL[1][i]);
            a0 += w[0] * x0[0] + w[1] * x0[1] + w[2] * x0[2] + w[3] * x0[3];
            a1 += w[0] * x1[0] + w[1] * x1[1] + w[2] * x1[2] + w[3] * x1[3];
        }
        kvn[0][t] = a0; kvn[1][t] = a1;
    }
    __syncthreads();
    // layernorm(g_tok, b_tok)
    for (int j = 0; j < 2; ++j) {
        float v = kvn[j][t];
        float s = v, s2 = v * v;
        for (int off = 32; off; off >>= 1) { s += __shfl_down(s, off); s2 += __shfl_down(s2, off); }
        if (lane == 0) { red[t >> 6] = s; red[4 + (t >> 6)] = s2; }
        __syncthreads();
        float S = red[0] + red[1] + red[2] + red[3];
        float S2 = red[4] + red[5] + red[6] + red[7];
        float m = S * (1.f / E);
        float rs = rsqrtf(S2 * (1.f / E) - m * m + 1e-5f);
        __syncthreads();
        kvn[j][t] = (v - m) * rs * g_tok[t] + b_tok[t];
    }
    __syncthreads();
    // k, v projections (row reads shared across tokens)
    {
        float k0 = bk[t], k1 = k0, v0 = bv[t], v1 = v0;
        const float* wkr = Wk + (size_t)t * E;
        const float* wvr = Wv + (size_t)t * E;
        for (int i = 0; i < E; i += 4) {
            f32x4 wk4 = *(const f32x4*)(wkr + i);
            f32x4 wv4 = *(const f32x4*)(wvr + i);
            f32x4 x0 = *(const f32x4*)(&kvn[0][i]);
            f32x4 x1 = *(const f32x4*)(&kvn[1][i]);
            k0 += wk4[0] * x0[0] + wk4[1] * x0[1] + wk4[2] * x0[2] + wk4[3] * x0[3];
            k1 += wk4[0] * x1[0] + wk4[1] * x1[1] + wk4[2] * x1[2] + wk4[3] * x1[3];
            v0 += wv4[0] * x0[0] + wv4[1] * x0[1] + wv4[2] * x0[2] + wv4[3] * x0[3];
            v1 += wv4[0] * x1[0] + wv4[1] * x1[1] + wv4[2] * x1[2] + wv4[3] * x1[3];
        }
        ks[0][t] = k0; ks[1][t] = k1; vs[0][t] = v0; vs[1][t] = v1;
    }
    __syncthreads();
    const float inv = 0.17677669529663687f;  // 1/sqrt(32)
    const float gi = g_img[t], bimg = b_img[t];
    for (int c = 0; c < 16; ++c) {
        int j = c >> 3, h = c & 7;
        float awk = 0.f, awv = 0.f;
        const float* wqc = Wq + (size_t)(h * 32) * E + t;   // coalesced in t
        const float* wor = Wo + (size_t)t * E + h * 32;
        #pragma unroll
        for (int d = 0; d < 32; d += 4) {
            f32x4 kv = *(const f32x4*)(&ks[j][h * 32 + d]);
            f32x4 vv = *(const f32x4*)(&vs[j][h * 32 + d]);
            f32x4 wo4 = *(const f32x4*)(wor + d);
            awk += kv[0] * wqc[(size_t)(d + 0) * E] + kv[1] * wqc[(size_t)(d + 1) * E]
                 + kv[2] * wqc[(size_t)(d + 2) * E] + kv[3] * wqc[(size_t)(d + 3) * E];
            awv += wo4[0] * vv[0] + wo4[1] * vv[1] + wo4[2] * vv[2] + wo4[3] * vv[3];
        }
        float base = awk * inv;
        wkbf[(size_t)(bi * 16 + c) * E + t] = f2bf(gi * base);       // g-scaled
        wvbf[((size_t)(bi * E + t)) * 32 + c] = f2bf(awv);
        float rk = gi * base, rb = bimg * base;
        for (int off = 32; off; off >>= 1) { rk += __shfl_down(rk, off); rb += __shfl_down(rb, off); }
        if (lane == 0) { redk[c][t >> 6] = rk; redb[c][t >> 6] = rb; }
    }
    #pragma unroll
    for (int c = 16; c < 32; ++c) wvbf[((size_t)(bi * E + t)) * 32 + c] = 0;  // K=32 zero pad
    __syncthreads();
    if (t < 16) {
        int c = t, j = c >> 3, h = c & 7;
        float s = 0.f;
        for (int d = 0; d < 32; ++d) s += bq[h * 32 + d] * ks[j][h * 32 + d];
        Gk[bi * 16 + c] = redk[c][0] + redk[c][1] + redk[c][2] + redk[c][3];
        sbk[bi * 16 + c] = redb[c][0] + redb[c][1] + redb[c][2] + redb[c][3] + s * inv;
    }
}

// ---------------- fused main: 64 rows/block, 512 threads (8 waves) ----------------
__global__ __launch_bounds__(512, 4) void fused_main_kernel(
    const float* __restrict__ img,
    const float* __restrict__ pbo, const float* __restrict__ pb2,
    const unsigned short* __restrict__ w1b, const unsigned short* __restrict__ w2b,
    const unsigned short* __restrict__ wkbf, const unsigned short* __restrict__ wvbf,
    const float* __restrict__ Gk, const float* __restrict__ sbk,
    const float* __restrict__ G1, const float* __restrict__ B1,
    float* __restrict__ out)
{
    __shared__ __align__(16) char smem[67584];
    unsigned short (*xs)[XS_LD] = (unsigned short(*)[XS_LD])smem;             // x, then x1 (bf16)
    unsigned short (*hs)[HS_LD] = (unsigned short(*)[HS_LD])(smem + 33792);   // gelu chunk (FFN)
    unsigned short (*al)[A_LD]  = (unsigned short(*)[A_LD])(smem + 33792);    // attn weights (pre-FFN, aliases hs)
    float (*outs)[OUT_LD] = (float(*)[OUT_LD])smem;                           // epilogue (aliases all)
    __shared__ float mean_s[BM], rstd_s[BM];

    const int t = threadIdx.x;
    const int lane = t & 63;
    const int wid = t >> 6;
    const int l15 = lane & 15;
    const int l4 = lane >> 4;
    const int bi = blockIdx.x >> 6;
    const int n0 = (blockIdx.x & 63) << 6;
    const int nc = wid * 32;   // this wave's 32 output cols

    const float* imgb = img + (size_t)bi * E * NTOK + n0;

    // P0: transpose load -> bf16 xs
    for (int e0 = 0; e0 < E; e0 += 8) {
        int e = e0 + wid;
        xs[lane][e] = f2bf(imgb[(size_t)e * NTOK + lane]);
    }
    __syncthreads();

    // P1: LN1 stats (wave owns 8 rows)
    for (int rr = 0; rr < 8; ++rr) {
        int r = wid * 8 + rr;
        ushort4 xv = *(const ushort4*)&xs[r][lane * 4];
        float v0 = bf2f(xv.x), v1 = bf2f(xv.y), v2 = bf2f(xv.z), v3 = bf2f(xv.w);
        float s = v0 + v1 + v2 + v3;
        float s2 = v0 * v0 + v1 * v1 + v2 * v2 + v3 * v3;
        for (int off = 32; off; off >>= 1) { s += __shfl_down(s, off); s2 += __shfl_down(s2, off); }
        if (lane == 0) {
            float m = s * (1.f / E);
            mean_s[r] = m;
            rstd_s[r] = rsqrtf(s2 * (1.f / E) - m * m + 1e-5f);
        }
    }
    __syncthreads();

    // P3a: scores via MFMA on raw x (LN1 folded: s = rs*(x@wk' - m*Gk) + sbk), softmax via shfl_xor
    if (wid < 4) {
        f32x4 p = {0.f, 0.f, 0.f, 0.f};
        for (int kk = 0; kk < 8; ++kk) {
            bf16x8 a = *(const bf16x8*)&xs[wid * 16 + l15][kk * 32 + l4 * 8];
            bf16x8 b = *(const bf16x8*)&wkbf[(size_t)(bi * 16 + l15) * E + kk * 32 + l4 * 8];
            p = __builtin_amdgcn_mfma_f32_16x16x32_bf16(a, b, p, 0, 0, 0);
        }
        float gkv = Gk[bi * 16 + l15];
        float sbv = sbk[bi * 16 + l15];
        #pragma unroll
        for (int rg = 0; rg < 4; ++rg) {
            int R = wid * 16 + l4 * 4 + rg;
            float s = rstd_s[R] * (p[rg] - mean_s[R] * gkv) + sbv;
            float sp = __shfl_xor(s, 8);           // partner token (c ^ 8), same row
            float mx = fmaxf(s, sp);
            float e0 = __expf(s - mx), e1 = __expf(sp - mx);
            al[R][l15] = f2bf(e0 / (e0 + e1));
            al[R][16 + l15] = 0;                   // K=32 zero pad
        }
    }
    __syncthreads();

    // P3c: attended via one K=32 MFMA per tile; x1 kept in f32 regs, bf16 copy to xs
    f32x4 acc2[4][2];
    {
        f32x4 pa[4][2];
        #pragma unroll
        for (int m = 0; m < 4; ++m)
            #pragma unroll
            for (int n = 0; n < 2; ++n)
                pa[m][n] = f32x4{0.f, 0.f, 0.f, 0.f};
        bf16x8 bv[2];
        #pragma unroll
        for (int n = 0; n < 2; ++n)
            bv[n] = *(const bf16x8*)&wvbf[((size_t)(bi * E + nc + n * 16 + l15)) * 32 + l4 * 8];
        #pragma unroll
        for (int m = 0; m < 4; ++m) {
            bf16x8 af = *(const bf16x8*)&al[m * 16 + l15][l4 * 8];
            #pragma unroll
            for (int n = 0; n < 2; ++n)
                pa[m][n] = __builtin_amdgcn_mfma_f32_16x16x32_bf16(af, bv[n], pa[m][n], 0, 0, 0);
        }
        float bov[2], b2v[2];
        #pragma unroll
        for (int n = 0; n < 2; ++n) {
            bov[n] = pbo[nc + n * 16 + l15];
            b2v[n] = pb2[nc + n * 16 + l15];
        }
        #pragma unroll
        for (int m = 0; m < 4; ++m)
            #pragma unroll
            for (int n = 0; n < 2; ++n)
                #pragma unroll
                for (int rg = 0; rg < 4; ++rg) {
                    int R = m * 16 + l4 * 4 + rg;
                    int C = nc + n * 16 + l15;
                    float x1 = bf2f(xs[R][C]) + pa[m][n][rg] + bov[n];
                    xs[R][C] = f2bf(x1);
                    acc2[m][n][rg] = x1 + b2v[n];   // FFN acc seeded with x1 + b2
                }
    }
    __syncthreads();

    // P4: LN2 stats on x1
    for (int rr = 0; rr < 8; ++rr) {
        int r = wid * 8 + rr;
        ushort4 xv = *(const ushort4*)&xs[r][lane * 4];
        float v0 = bf2f(xv.x), v1 = bf2f(xv.y), v2 = bf2f(xv.z), v3 = bf2f(xv.w);
        float s = v0 + v1 + v2 + v3;
        float s2 = v0 * v0 + v1 * v1 + v2 * v2 + v3 * v3;
        for (int off = 32; off; off >>= 1) { s += __shfl_down(s, off); s2 += __shfl_down(s2, off); }
        if (lane == 0) {
            float m = s * (1.f / E);
            mean_s[r] = m;
            rstd_s[r] = rsqrtf(s2 * (1.f / E) - m * m + 1e-5f);
        }
    }
    __syncthreads();

    // FFN: GEMM1 on raw x1 (LN2 folded), gelu -> hs, GEMM2 into acc2
    for (int fc = 0; fc < FF; fc += 256) {
        f32x4 p[4][2];
        #pragma unroll
        for (int m = 0; m < 4; ++m)
            #pragma unroll
            for (int n = 0; n < 2; ++n)
                p[m][n] = f32x4{0.f, 0.f, 0.f, 0.f};
        for (int kk = 0; kk < 8; ++kk) {
            bf16x8 af[4], bfr[2];
            #pragma unroll
            for (int m = 0; m < 4; ++m)
                af[m] = *(const bf16x8*)&xs[m * 16 + l15][kk * 32 + l4 * 8];
            #pragma unroll
            for (int n = 0; n < 2; ++n)
                bfr[n] = *(const bf16x8*)&w1b[(size_t)(fc + nc + n * 16 + l15) * E + kk * 32 + l4 * 8];
            #pragma unroll
            for (int m = 0; m < 4; ++m)
                #pragma unroll
                for (int n = 0; n < 2; ++n)
                    p[m][n] = __builtin_amdgcn_mfma_f32_16x16x32_bf16(af[m], bfr[n], p[m][n], 0, 0, 0);
        }
        {
            float g1v[2], b1v[2];
            #pragma unroll
            for (int n = 0; n < 2; ++n) {
                g1v[n] = G1[fc + nc + n * 16 + l15];
                b1v[n] = B1[fc + nc + n * 16 + l15];
            }
            #pragma unroll
            for (int m = 0; m < 4; ++m)
                #pragma unroll
                for (int n = 0; n < 2; ++n)
                    #pragma unroll
                    for (int rg = 0; rg < 4; ++rg) {
                        int R = m * 16 + l4 * 4 + rg;
                        float hpre = rstd_s[R] * (p[m][n][rg] - mean_s[R] * g1v[n]) + b1v[n];
                        hs[R][nc + n * 16 + l15] = f2bf(gelu_tanh(hpre));
                    }
        }
        __syncthreads();
        for (int kk = 0; kk < 8; ++kk) {
            bf16x8 af[4], bfr[2];
            #pragma unroll
            for (int m = 0; m < 4; ++m)
                af[m] = *(const bf16x8*)&hs[m * 16 + l15][kk * 32 + l4 * 8];
            #pragma unroll
            for (int n = 0; n < 2; ++n)
                bfr[n] = *(const bf16x8*)&w2b[(size_t)(nc + n * 16 + l15) * FF + fc + kk * 32 + l4 * 8];
            #pragma unroll
            for (int m = 0; m < 4; ++m)
                #pragma unroll
                for (int n = 0; n < 2; ++n)
                    acc2[m][n] = __builtin_amdgcn_mfma_f32_16x16x32_bf16(af[m], bfr[n], acc2[m][n], 0, 0, 0);
        }
        __syncthreads();
    }

    // Epilogue: acc2 already = x1 + b2 + ffn
    #pragma unroll
    for (int m = 0; m < 4; ++m)
        #pragma unroll
        for (int n = 0; n < 2; ++n)
            #pragma unroll
            for (int rg = 0; rg < 4; ++rg)
                outs[m * 16 + l4 * 4 + rg][nc + n * 16 + l15] = acc2[m][n][rg];
    __syncthreads();

    // transpose store
    float* outb = out + (size_t)bi * E * NTOK + n0;
    for (int e0 = 0; e0 < E; e0 += 8) {
        int e = e0 + wid;
        outb[(size_t)e * NTOK + lane] = outs[lane][e];
    }
}

extern "C" void kernel_launch(void* const* d_in, const int* in_sizes, int n_in,
                              void* d_out, int out_size, void* d_ws, size_t ws_size,
                              hipStream_t stream) {
    (void)in_sizes; (void)n_in; (void)out_size; (void)ws_size;
    const float* img   = (const float*)d_in[0];
    const float* tt    = (const float*)d_in[1];
    const float* bgt   = (const float*)d_in[2];
    const float* Wp    = (const float*)d_in[3];
    const float* bp    = (const float*)d_in[4];
    const float* g_img = (const float*)d_in[5];
    const float* b_img = (const float*)d_in[6];
    const float* g_tok = (const float*)d_in[7];
    const float* b_tok = (const float*)d_in[8];
    const float* g_ffn = (const float*)d_in[9];
    const float* b_ffn = (const float*)d_in[10];
    const float* Wq    = (const float*)d_in[11];
    const float* Wk    = (const float*)d_in[12];
    const float* Wv    = (const float*)d_in[13];
    const float* bq    = (const float*)d_in[14];
    const float* bk    = (const float*)d_in[15];
    const float* bv    = (const float*)d_in[16];
    const float* Wo    = (const float*)d_in[17];
    const float* bo    = (const float*)d_in[18];
    const float* W1    = (const float*)d_in[19];
    const float* b1    = (const float*)d_in[20];
    const float* W2    = (const float*)d_in[21];
    const float* b2    = (const float*)d_in[22];

    char* ws = (char*)d_ws;
    unsigned short* w1b  = (unsigned short*)(ws);                 // 512 KB (g_ffn-scaled)
    unsigned short* w2b  = (unsigned short*)(ws + 524288);        // 512 KB
    unsigned short* wkbf = (unsigned short*)(ws + 1048576);       // 128 KB [b][c][k] (g_img-scaled)
    unsigned short* wvbf = (unsigned short*)(ws + 1179648);       // 256 KB [b][o][k=32 padded]
    float*          Gk   = (float*)(ws + 1441792);                // 1 KB
    float*          sbk  = (float*)(ws + 1442816);                // 1 KB
    float*          G1   = (float*)(ws + 1443840);                // 4 KB
    float*          B1   = (float*)(ws + 1447936);                // 4 KB

    hipLaunchKernelGGL(prep_kernel, dim3(272), dim3(256), 0, stream,
                       W1, W2, b1, tt, bgt, Wp, bp, g_tok, b_tok, g_img, b_img,
                       Wq, bq, Wk, bk, Wv, bv, Wo, g_ffn, b_ffn,
                       w1b, w2b, wkbf, wvbf, Gk, sbk, G1, B1);
    hipLaunchKernelGGL(fused_main_kernel, dim3(1024), dim3(512), 0, stream,
                       img, bo, b2, w1b, w2b, wkbf, wvbf, Gk, sbk, G1, B1, (float*)d_out);
}